// Round 22
// baseline (315.341 us; speedup 1.0000x reference)
//
#include <hip/hip_runtime.h>
#include <hip/hip_fp16.h>
#include <math.h>

#define NFEAT 256
#define HID 64
#define NCLS 6
#define NBMX 1600       // LDS sizing (nbuck = 1563)
#define CAPB 4096       // k_build LDS buffer bound (bucket mean 2048, 8+ sd headroom)
#define CHUNK 8192      // edges per count/scatter block (391 blocks: shorter serial chains)
#define XPAD 68         // Xl row stride (floats)
#define FUSED_LDS ((4096 + 64 * XPAD) * 4)  // gemm branch 33.4KB; others smaller
#define TILES_CNT 280   // gemm1 tiles hosted by k_count_f
#define TILES_SCN 320   // gemm1 tiles hosted by k_scan_f

typedef float vf4 __attribute__((ext_vector_type(4)));
typedef int   vi4 __attribute__((ext_vector_type(4)));

// ---------------- gemm1 tile body (unscaled fp16 out), shared by the fused kernels ----------------

__device__ __forceinline__ void gemm1_tile(char* smem, int tile, int t,
                                           const float* __restrict__ X,
                                           const float* __restrict__ W1,
                                           __half* __restrict__ H16, int n) {
  float* Wl = (float*)smem;          // 64*64
  float* Xl = Wl + 4096;             // 64 rows, stride XPAD
  const int row0 = tile * 64;
  const int tc = t & 15;
  const int tr = t >> 4;
  float acc[4][4] = {};

  for (int k0 = 0; k0 < NFEAT; k0 += 64) {
    __syncthreads();
#pragma unroll
    for (int i = 0; i < 4; ++i) {
      int idx = t * 4 + i * 1024;
      int kr = idx >> 6, c = idx & 63;
      *(vf4*)&Wl[idx] = *(const vf4*)&W1[(size_t)(k0 + kr) * 64 + c];
    }
#pragma unroll
    for (int i = 0; i < 4; ++i) {
      int idx = t * 4 + i * 1024;
      int r = idx >> 6, c = idx & 63;
      int row = row0 + r;
      vf4 v = {0.f, 0.f, 0.f, 0.f};
      if (row < n) v = __builtin_nontemporal_load((const vf4*)&X[(size_t)row * NFEAT + k0 + c]);
      *(vf4*)&Xl[r * XPAD + c] = v;
    }
    __syncthreads();
#pragma unroll 4
    for (int kk = 0; kk < 64; kk += 4) {
      float4 xv[4], wv[4];
#pragma unroll
      for (int r = 0; r < 4; ++r) xv[r] = *(float4*)&Xl[(tr * 4 + r) * XPAD + kk];
#pragma unroll
      for (int q = 0; q < 4; ++q) wv[q] = *(float4*)&Wl[(kk + q) * 64 + tc * 4];
#pragma unroll
      for (int r = 0; r < 4; ++r) {
        const float xr[4] = {xv[r].x, xv[r].y, xv[r].z, xv[r].w};
#pragma unroll
        for (int q = 0; q < 4; ++q) {
          acc[r][0] += xr[q] * wv[q].x;
          acc[r][1] += xr[q] * wv[q].y;
          acc[r][2] += xr[q] * wv[q].z;
          acc[r][3] += xr[q] * wv[q].w;
        }
      }
    }
  }
#pragma unroll
  for (int r = 0; r < 4; ++r) {
    int row = row0 + tr * 4 + r;
    if (row < n) {
      __half2 h01 = __floats2half2_rn(acc[r][0], acc[r][1]);
      __half2 h23 = __floats2half2_rn(acc[r][2], acc[r][3]);
      uint2 st;
      st.x = *reinterpret_cast<unsigned*>(&h01);
      st.y = *reinterpret_cast<unsigned*>(&h23);
      ((uint2*)H16)[(size_t)row * 16 + tc] = st;
    }
  }
}

// ---------------- pass 1 FUSED: per-block histogram (blocks < nbb) || gemm1 tiles [0, TILES_CNT) ----------------

__global__ __launch_bounds__(256) void k_count_f(const int* __restrict__ dst,
                                                 int* __restrict__ C, int E, int nbuck, int nbb,
                                                 const float* __restrict__ X,
                                                 const float* __restrict__ W1,
                                                 __half* __restrict__ H16, int n) {
  extern __shared__ char smem[];
  int t = threadIdx.x;
  if (blockIdx.x < nbb) {
    int* cnt = (int*)smem;  // NBMX
    for (int i = t; i < nbuck; i += 256) cnt[i] = 0;
    __syncthreads();
    int e0 = blockIdx.x * CHUNK;
    int e1 = e0 + CHUNK;
    if (e1 > E) e1 = E;
    for (int r0 = e0; r0 < e1; r0 += 1024) {
      int i0 = r0 + t * 4;
      if (i0 + 4 <= e1) {
        vi4 dv = __builtin_nontemporal_load((const vi4*)&dst[i0]);
        atomicAdd(&cnt[dv.x >> 6], 1);
        atomicAdd(&cnt[dv.y >> 6], 1);
        atomicAdd(&cnt[dv.z >> 6], 1);
        atomicAdd(&cnt[dv.w >> 6], 1);
      } else {
        for (int q = 0; q < 4; ++q)
          if (i0 + q < e1) atomicAdd(&cnt[dst[i0 + q] >> 6], 1);
      }
    }
    __syncthreads();
    int* Crow = C + (size_t)blockIdx.x * nbuck;
    for (int i = t; i < nbuck; i += 256) Crow[i] = cnt[i];
  } else {
    gemm1_tile(smem, (int)blockIdx.x - nbb, t, X, W1, H16, n);
  }
}

// ---------------- pass 2a FUSED: column prefix (blocks < nsb) || gemm1 tiles [TILES_CNT, +TILES_SCN) ----------------

__global__ __launch_bounds__(256) void k_scan_f(int* __restrict__ C,
                                                int* __restrict__ T,
                                                int nblk, int nbuck, int nsb,
                                                const float* __restrict__ X,
                                                const float* __restrict__ W1,
                                                __half* __restrict__ H16, int n, int tile0) {
  extern __shared__ char smem[];
  int t = threadIdx.x;
  if (blockIdx.x < (unsigned)nsb) {
    int b = blockIdx.x * 256 + t;
    if (b >= nbuck) return;
    int run = 0;
    int blk = 0;
    for (; blk + 4 <= nblk; blk += 4) {
      int c0 = C[(size_t)(blk + 0) * nbuck + b];
      int c1 = C[(size_t)(blk + 1) * nbuck + b];
      int c2 = C[(size_t)(blk + 2) * nbuck + b];
      int c3 = C[(size_t)(blk + 3) * nbuck + b];
      C[(size_t)(blk + 0) * nbuck + b] = run; run += c0;
      C[(size_t)(blk + 1) * nbuck + b] = run; run += c1;
      C[(size_t)(blk + 2) * nbuck + b] = run; run += c2;
      C[(size_t)(blk + 3) * nbuck + b] = run; run += c3;
    }
    for (; blk < nblk; ++blk) {
      int c = C[(size_t)blk * nbuck + b];
      C[(size_t)blk * nbuck + b] = run;
      run += c;
    }
    T[b] = run;
  } else {
    gemm1_tile(smem, tile0 + (int)blockIdx.x - nsb, t, X, W1, H16, n);
  }
}

// ---------------- pass 2b: exclusive scan of T -> bbase ----------------

__global__ __launch_bounds__(256) void k_scanb(const int* __restrict__ T,
                                               int* __restrict__ bbase, int nbuck) {
  __shared__ int sh[256];
  __shared__ int carry;
  int t = threadIdx.x;
  if (t == 0) carry = 0;
  __syncthreads();
  for (int base = 0; base < nbuck; base += 256) {
    int v = (base + t < nbuck) ? T[base + t] : 0;
    sh[t] = v;
    __syncthreads();
    for (int off = 1; off < 256; off <<= 1) {
      int x = sh[t];
      int y = (t >= off) ? sh[t - off] : 0;
      __syncthreads();
      sh[t] = x + y;
      __syncthreads();
    }
    if (base + t < nbuck) bbase[base + t] = carry + sh[t] - v;
    __syncthreads();
    if (t == 255) carry += sh[255];
    __syncthreads();
  }
}

// ---------------- pass 3 FUSED: bucket-major scatter (blocks < nbb) || gemm1 tiles [tile0, ntile) ----------------

__global__ __launch_bounds__(256) void k_fused(const int* __restrict__ src,
                                               const int* __restrict__ dst,
                                               const int* __restrict__ C,
                                               const int* __restrict__ bbase,
                                               unsigned* __restrict__ packed,
                                               int E, int nbuck, int nbb,
                                               const float* __restrict__ X,
                                               const float* __restrict__ W1,
                                               __half* __restrict__ H16, int n, int tile0) {
  extern __shared__ char smem[];
  int t = threadIdx.x;

  if (blockIdx.x < nbb) {
    int* baseL = (int*)smem;            // NBMX
    int* cnt   = baseL + NBMX;          // NBMX
    const int* Crow = C + (size_t)blockIdx.x * nbuck;
    for (int i = t; i < nbuck; i += 256) {
      baseL[i] = bbase[i] + Crow[i];
      cnt[i] = 0;
    }
    __syncthreads();

    int e0 = blockIdx.x * CHUNK;
    int e1 = e0 + CHUNK;
    if (e1 > E) e1 = E;
    for (int r0 = e0; r0 < e1; r0 += 1024) {
      int i0 = r0 + t * 4;
      int s4[4], d4[4];
      bool full = (i0 + 4 <= e1);
      if (full) {
        vi4 sv = __builtin_nontemporal_load((const vi4*)&src[i0]);
        vi4 dv = __builtin_nontemporal_load((const vi4*)&dst[i0]);
        s4[0] = sv.x; s4[1] = sv.y; s4[2] = sv.z; s4[3] = sv.w;
        d4[0] = dv.x; d4[1] = dv.y; d4[2] = dv.z; d4[3] = dv.w;
      } else {
        for (int q = 0; q < 4; ++q)
          if (i0 + q < e1) { s4[q] = src[i0 + q]; d4[q] = dst[i0 + q]; }
      }
#pragma unroll
      for (int q = 0; q < 4; ++q) {
        if (i0 + q < e1) {
          int b = d4[q] >> 6;
          int slot = atomicAdd(&cnt[b], 1);
          packed[(size_t)baseL[b] + slot] =
              ((unsigned)s4[q] << 6) | (unsigned)(d4[q] & 63);
        }
      }
    }
  } else {
    gemm1_tile(smem, tile0 + (int)blockIdx.x - nbb, t, X, W1, H16, n);
  }
}

// ---------------- build: in-LDS counting sort + in-place dis-scaling of this bucket's g1 rows ----------------

__global__ __launch_bounds__(256) void k_build(unsigned* __restrict__ packed,
                                               const int* __restrict__ T,
                                               const int* __restrict__ bbase,
                                               int2* __restrict__ rowrange,
                                               float* __restrict__ dis,
                                               __half* __restrict__ g1,
                                               int n, int nbuck) {
  __shared__ unsigned buf[CAPB];
  __shared__ unsigned outb[CAPB];
  __shared__ int cnt4[4][64];
  __shared__ int cur4[4][64];
  __shared__ int offi[64];
  __shared__ int offx[64];
  __shared__ int cntl[64];
  __shared__ float disl[64];
  int b = blockIdx.x;
  int t = threadIdx.x;
  int g = t >> 6;
  int m = T[b];
  if (m > CAPB) m = CAPB;
  int bb = bbase[b];
  unsigned* pb = packed + bb;

  cnt4[g][t & 63] = 0;
  for (int k = t; k < m; k += 256) buf[k] = pb[k];
  __syncthreads();
  for (int k = t; k < m; k += 256) atomicAdd(&cnt4[g][buf[k] & 63u], 1);
  __syncthreads();
  if (t < 64) {
    int c0 = cnt4[0][t], c1 = cnt4[1][t], c2 = cnt4[2][t], c3 = cnt4[3][t];
    int tot = c0 + c1 + c2 + c3;
    cntl[t] = tot;
    offi[t] = tot;
    cur4[0][t] = 0;
    cur4[1][t] = c0;
    cur4[2][t] = c0 + c1;
    cur4[3][t] = c0 + c1 + c2;
  }
  __syncthreads();
  for (int off = 1; off < 64; off <<= 1) {
    int x = (t < 64) ? offi[t] : 0;
    int y = (t >= off && t < 64) ? offi[t - off] : 0;
    __syncthreads();
    if (t < 64) offi[t] = x + y;
    __syncthreads();
  }
  if (t < 64) {
    offx[t] = offi[t] - cntl[t];
    float dv = rsqrtf((float)cntl[t] + 1.0f);  // +1 self-loop
    disl[t] = dv;
    int v = b * 64 + t;
    if (v < n) {
      rowrange[v] = make_int2(bb + offx[t], cntl[t]);
      dis[v] = dv;
    }
#pragma unroll
    for (int gg = 0; gg < 4; ++gg) cur4[gg][t] += offx[t];
  }
  __syncthreads();
  for (int k = t; k < m; k += 256) {
    unsigned e = buf[k];
    int dl = e & 63u;
    int q = atomicAdd(&cur4[g][dl], 1);
    outb[q] = e >> 6;
  }
  __syncthreads();
  for (int k = t; k < m; k += 256) pb[k] = outb[k];  // packed becomes srcs

  __half2* g1h = (__half2*)g1;
#pragma unroll
  for (int i = 0; i < 8; ++i) {
    int idx = t + i * 256;            // 0..2047
    int r = idx >> 5, e = idx & 31;
    int v = b * 64 + r;
    if (v < n) {
      size_t p = (size_t)v * 32 + e;
      float2 f = __half22float2(g1h[p]);
      float d = disl[r];
      g1h[p] = __floats2half2_rn(f.x * d, f.y * d);
    }
  }
}

// ---------------- FUSED layer 1: agg (pre-scaled msgs) + ReLU + @W2 (in-group shfl) -> g2 fp16 ----------------

__global__ __launch_bounds__(256) void k_agg_gemm(const int2* __restrict__ rowrange,
                                                  const int* __restrict__ srcs,
                                                  const __half* __restrict__ g16,
                                                  const float* __restrict__ dis,
                                                  const float* __restrict__ b1,
                                                  const float* __restrict__ W2,
                                                  __half* __restrict__ g2out, int n) {
  __shared__ __half2 W2h[64 * 32];  // 8KB
  int t = threadIdx.x;
  for (int i = t; i < 2048; i += 256) {
    float2 f = *(const float2*)&W2[(size_t)i * 2];
    W2h[i] = __floats2half2_rn(f.x, f.y);
  }
  __syncthreads();  // W2h ready BEFORE gather; no sync after

  int grp = t >> 4, lane = t & 15;
  int v = blockIdx.x * 16 + grp;
  if (v >= n) return;
  const uint2* g2 = (const uint2*)g16;

  int2 rr = rowrange[v];
  int j = rr.x, end = rr.x + rr.y;
  uint2 su = g2[(size_t)v * 16 + lane];
  float2 f0 = __half22float2(*reinterpret_cast<__half2*>(&su.x));
  float2 f1 = __half22float2(*reinterpret_cast<__half2*>(&su.y));
  float ax = f0.x, ay = f0.y, az = f1.x, aw = f1.y;

  for (; j + 8 <= end; j += 8) {
    int s[8];
#pragma unroll
    for (int q = 0; q < 8; ++q) s[q] = __builtin_nontemporal_load(&srcs[j + q]);
    uint2 a[8];
#pragma unroll
    for (int q = 0; q < 8; ++q) a[q] = g2[(size_t)s[q] * 16 + lane];
#pragma unroll
    for (int q = 0; q < 8; ++q) {
      float2 p0 = __half22float2(*reinterpret_cast<__half2*>(&a[q].x));
      float2 p1 = __half22float2(*reinterpret_cast<__half2*>(&a[q].y));
      ax += p0.x; ay += p0.y; az += p1.x; aw += p1.y;
    }
  }
  for (; j < end; ++j) {
    int s0 = __builtin_nontemporal_load(&srcs[j]);
    uint2 a0 = g2[(size_t)s0 * 16 + lane];
    float2 p0 = __half22float2(*reinterpret_cast<__half2*>(&a0.x));
    float2 p1 = __half22float2(*reinterpret_cast<__half2*>(&a0.y));
    ax += p0.x; ay += p0.y; az += p1.x; aw += p1.y;
  }

  float dv = dis[v];
  float4 bb = *(const float4*)&b1[lane * 4];
  float r0 = fmaxf(fmaf(dv, ax, bb.x), 0.f);
  float r1 = fmaxf(fmaf(dv, ay, bb.y), 0.f);
  float r2 = fmaxf(fmaf(dv, az, bb.z), 0.f);
  float r3 = fmaxf(fmaf(dv, aw, bb.w), 0.f);

  float o0 = 0.f, o1 = 0.f, o2 = 0.f, o3 = 0.f;
  int gbase = (t & 63) & 48;
  int c2 = lane * 2;
#pragma unroll
  for (int kk = 0; kk < 16; ++kk) {
    int sl = gbase + kk;
    float a0 = __shfl(r0, sl, 64);
    float a1 = __shfl(r1, sl, 64);
    float a2 = __shfl(r2, sl, 64);
    float a3 = __shfl(r3, sl, 64);
    int k = kk * 4;
    float2 w;
    w = __half22float2(W2h[(k + 0) * 32 + c2]);     o0 = fmaf(a0, w.x, o0); o1 = fmaf(a0, w.y, o1);
    w = __half22float2(W2h[(k + 0) * 32 + c2 + 1]); o2 = fmaf(a0, w.x, o2); o3 = fmaf(a0, w.y, o3);
    w = __half22float2(W2h[(k + 1) * 32 + c2]);     o0 = fmaf(a1, w.x, o0); o1 = fmaf(a1, w.y, o1);
    w = __half22float2(W2h[(k + 1) * 32 + c2 + 1]); o2 = fmaf(a1, w.x, o2); o3 = fmaf(a1, w.y, o3);
    w = __half22float2(W2h[(k + 2) * 32 + c2]);     o0 = fmaf(a2, w.x, o0); o1 = fmaf(a2, w.y, o1);
    w = __half22float2(W2h[(k + 2) * 32 + c2 + 1]); o2 = fmaf(a2, w.x, o2); o3 = fmaf(a2, w.y, o3);
    w = __half22float2(W2h[(k + 3) * 32 + c2]);     o0 = fmaf(a3, w.x, o0); o1 = fmaf(a3, w.y, o1);
    w = __half22float2(W2h[(k + 3) * 32 + c2 + 1]); o2 = fmaf(a3, w.x, o2); o3 = fmaf(a3, w.y, o3);
  }
  __half2 h01 = __floats2half2_rn(o0 * dv, o1 * dv);
  __half2 h23 = __floats2half2_rn(o2 * dv, o3 * dv);
  uint2 st;
  st.x = *reinterpret_cast<unsigned*>(&h01);
  st.y = *reinterpret_cast<unsigned*>(&h23);
  ((uint2*)g2out)[(size_t)v * 16 + lane] = st;
}

// ---------------- FUSED layer 2: agg (pre-scaled msgs) + ReLU + @Wfc + bfc -> out ----------------

__global__ __launch_bounds__(256) void k_agg_fc(const int2* __restrict__ rowrange,
                                                const int* __restrict__ srcs,
                                                const __half* __restrict__ g16,
                                                const float* __restrict__ dis,
                                                const float* __restrict__ b2,
                                                const float* __restrict__ Wfc,
                                                const float* __restrict__ bfc,
                                                float* __restrict__ outp, int n) {
  __shared__ float Wl[64 * NCLS];
  __shared__ float bl[8];
  int t = threadIdx.x;
  for (int i = t; i < 64 * NCLS; i += 256) Wl[i] = Wfc[i];
  if (t < NCLS) bl[t] = bfc[t];
  __syncthreads();

  int grp = t >> 4, lane = t & 15;
  int v = blockIdx.x * 16 + grp;
  bool active = (v < n);
  const uint2* g2 = (const uint2*)g16;

  float r0 = 0.f, r1 = 0.f, r2 = 0.f, r3 = 0.f;
  if (active) {
    int2 rr = rowrange[v];
    int j = rr.x, end = rr.x + rr.y;
    uint2 su = g2[(size_t)v * 16 + lane];
    float2 f0 = __half22float2(*reinterpret_cast<__half2*>(&su.x));
    float2 f1 = __half22float2(*reinterpret_cast<__half2*>(&su.y));
    float ax = f0.x, ay = f0.y, az = f1.x, aw = f1.y;

    for (; j + 8 <= end; j += 8) {
      int s[8];
#pragma unroll
      for (int q = 0; q < 8; ++q) s[q] = __builtin_nontemporal_load(&srcs[j + q]);
      uint2 a[8];
#pragma unroll
      for (int q = 0; q < 8; ++q) a[q] = g2[(size_t)s[q] * 16 + lane];
#pragma unroll
      for (int q = 0; q < 8; ++q) {
        float2 p0 = __half22float2(*reinterpret_cast<__half2*>(&a[q].x));
        float2 p1 = __half22float2(*reinterpret_cast<__half2*>(&a[q].y));
        ax += p0.x; ay += p0.y; az += p1.x; aw += p1.y;
      }
    }
    for (; j < end; ++j) {
      int s0 = __builtin_nontemporal_load(&srcs[j]);
      uint2 a0 = g2[(size_t)s0 * 16 + lane];
      float2 p0 = __half22float2(*reinterpret_cast<__half2*>(&a0.x));
      float2 p1 = __half22float2(*reinterpret_cast<__half2*>(&a0.y));
      ax += p0.x; ay += p0.y; az += p1.x; aw += p1.y;
    }
    float dv = dis[v];
    float4 bb = *(const float4*)&b2[lane * 4];
    r0 = fmaxf(fmaf(dv, ax, bb.x), 0.f);
    r1 = fmaxf(fmaf(dv, ay, bb.y), 0.f);
    r2 = fmaxf(fmaf(dv, az, bb.z), 0.f);
    r3 = fmaxf(fmaf(dv, aw, bb.w), 0.f);
  }

  float p[NCLS];
#pragma unroll
  for (int jj = 0; jj < NCLS; ++jj) p[jj] = 0.f;
  int k0 = lane * 4;
#pragma unroll
  for (int q = 0; q < 4; ++q) {
    float a = (q == 0) ? r0 : (q == 1) ? r1 : (q == 2) ? r2 : r3;
#pragma unroll
    for (int jj = 0; jj < NCLS; ++jj)
      p[jj] = fmaf(a, Wl[(k0 + q) * NCLS + jj], p[jj]);
  }
#pragma unroll
  for (int m = 1; m < 16; m <<= 1) {
#pragma unroll
    for (int jj = 0; jj < NCLS; ++jj)
      p[jj] += __shfl_xor(p[jj], m, 64);
  }
  if (active && lane < NCLS)
    outp[(size_t)v * NCLS + lane] = p[lane] + bl[lane];
}

// ---------------- launch ----------------

extern "C" void kernel_launch(void* const* d_in, const int* in_sizes, int n_in,
                              void* d_out, int out_size, void* d_ws, size_t ws_size,
                              hipStream_t stream) {
  const float* x   = (const float*)d_in[0];
  const int*   ei  = (const int*)d_in[1];
  const float* W1  = (const float*)d_in[2];
  const float* b1  = (const float*)d_in[3];
  const float* W2  = (const float*)d_in[4];
  const float* b2  = (const float*)d_in[5];
  const float* Wfc = (const float*)d_in[6];
  const float* bfc = (const float*)d_in[7];
  float* out = (float*)d_out;

  const int n = in_sizes[0] / NFEAT;   // 100000
  const int E = in_sizes[1] / 2;       // 3200000
  const int* src = ei;
  const int* dst = ei + E;
  const int nbuck = (n + 63) >> 6;     // 1563 (<= NBMX)
  const int nbb = (E + CHUNK - 1) / CHUNK;  // 391 count/scatter blocks
  const int ntile = (n + 63) / 64;     // 1563 gemm tiles
  const int nsb = (nbuck + 255) / 256; // 7 scan blocks
  int tc = TILES_CNT, ts = TILES_SCN;
  if (tc > ntile) tc = ntile;
  if (tc + ts > ntile) ts = ntile - tc;
  const int tf = ntile - tc - ts;      // tiles in k_fused

  char* ws = (char*)d_ws;
  size_t off = 0;
  auto alloc = [&](size_t bytes) -> void* {
    void* p = (void*)(ws + off);
    off += (bytes + 255) & ~(size_t)255;
    return p;
  };
  float* dis      = (float*)alloc((size_t)n * 4);
  int2*  rowrange = (int2*)alloc((size_t)n * 8);
  int*   C        = (int*)alloc((size_t)nbb * nbuck * 4);   // 2.4MB count matrix
  int*   T        = (int*)alloc((size_t)nbuck * 4);
  int*   bbase    = (int*)alloc((size_t)nbuck * 4);
  unsigned* packed = (unsigned*)alloc((size_t)E * 4);       // 12.8MB dense; becomes srcs
  __half* bufA16  = (__half*)alloc((size_t)n * HID * 2);    // g1 (12.8MB), dis-scaled by k_build
  __half* bufC16  = (__half*)alloc((size_t)n * HID * 2);    // g2 (12.8MB)

  // ---- deterministic 3-pass CSR build; every pass hosts gemm1 tiles ----
  k_count_f<<<nbb + tc, 256, FUSED_LDS, stream>>>(dst, C, E, nbuck, nbb, x, W1, bufA16, n);
  k_scan_f<<<nsb + ts, 256, FUSED_LDS, stream>>>(C, T, nbb, nbuck, nsb, x, W1, bufA16, n, tc);
  k_scanb<<<1, 256, 0, stream>>>(T, bbase, nbuck);
  k_fused<<<nbb + tf, 256, FUSED_LDS, stream>>>(src, dst, C, bbase, packed,
                                                E, nbuck, nbb, x, W1, bufA16, n, tc + ts);
  k_build<<<nbuck, 256, 0, stream>>>(packed, T, bbase, rowrange, dis, bufA16, n, nbuck);

  // ---- layer 1 agg + gemm2 fused -> g2 ----
  k_agg_gemm<<<(n + 15) / 16, 256, 0, stream>>>(rowrange, (const int*)packed, bufA16,
                                                dis, b1, W2, bufC16, n);

  // ---- layer 2 agg + FC fused -> out ----
  k_agg_fc<<<(n + 15) / 16, 256, 0, stream>>>(rowrange, (const int*)packed, bufC16,
                                              dis, b2, Wfc, bfc, out, n);
}

// Round 23
// 285.230 us; speedup vs baseline: 1.1056x; 1.1056x over previous
//
#include <hip/hip_runtime.h>
#include <hip/hip_fp16.h>
#include <math.h>

#define NFEAT 256
#define HID 64
#define NCLS 6
#define NBMX 1600       // LDS sizing (nbuck = 1563)
#define CAPB 4096       // k_build LDS buffer bound (bucket mean 2048, 8+ sd headroom)
#define CHUNK 16384     // edges per count/scatter block
#define XPAD 68         // Xl row stride (floats): 68%32=4 staggers banks across rows
#define FUSED_LDS ((4096 + 64 * XPAD) * 4)  // Wl 16KB + padded Xl 17.4KB = 33.4KB

typedef float vf4 __attribute__((ext_vector_type(4)));
typedef int   vi4 __attribute__((ext_vector_type(4)));

// ---------------- pass 1: per-block bucket histogram ----------------

__global__ __launch_bounds__(256) void k_count(const int* __restrict__ dst,
                                               int* __restrict__ C, int E, int nbuck) {
  __shared__ int cnt[NBMX];
  int t = threadIdx.x;
  for (int i = t; i < nbuck; i += 256) cnt[i] = 0;
  __syncthreads();
  int e0 = blockIdx.x * CHUNK;
  int e1 = e0 + CHUNK;
  if (e1 > E) e1 = E;
  for (int r0 = e0; r0 < e1; r0 += 1024) {
    int i0 = r0 + t * 4;
    if (i0 + 4 <= e1) {
      vi4 dv = __builtin_nontemporal_load((const vi4*)&dst[i0]);
      atomicAdd(&cnt[dv.x >> 6], 1);
      atomicAdd(&cnt[dv.y >> 6], 1);
      atomicAdd(&cnt[dv.z >> 6], 1);
      atomicAdd(&cnt[dv.w >> 6], 1);
    } else {
      for (int q = 0; q < 4; ++q)
        if (i0 + q < e1) atomicAdd(&cnt[dst[i0 + q] >> 6], 1);
    }
  }
  __syncthreads();
  int* Crow = C + (size_t)blockIdx.x * nbuck;
  for (int i = t; i < nbuck; i += 256) Crow[i] = cnt[i];
}

// ---------------- pass 2a: per-bucket column prefix over blocks ----------------

__global__ __launch_bounds__(256) void k_scan_cols(int* __restrict__ C,
                                                   int* __restrict__ T,
                                                   int nblk, int nbuck) {
  int b = blockIdx.x * 256 + threadIdx.x;
  if (b >= nbuck) return;
  int run = 0;
  int blk = 0;
  for (; blk + 4 <= nblk; blk += 4) {
    int c0 = C[(size_t)(blk + 0) * nbuck + b];
    int c1 = C[(size_t)(blk + 1) * nbuck + b];
    int c2 = C[(size_t)(blk + 2) * nbuck + b];
    int c3 = C[(size_t)(blk + 3) * nbuck + b];
    C[(size_t)(blk + 0) * nbuck + b] = run; run += c0;
    C[(size_t)(blk + 1) * nbuck + b] = run; run += c1;
    C[(size_t)(blk + 2) * nbuck + b] = run; run += c2;
    C[(size_t)(blk + 3) * nbuck + b] = run; run += c3;
  }
  for (; blk < nblk; ++blk) {
    int c = C[(size_t)blk * nbuck + b];
    C[(size_t)blk * nbuck + b] = run;
    run += c;
  }
  T[b] = run;
}

// ---------------- pass 2b: exclusive scan of T -> bbase ----------------

__global__ __launch_bounds__(256) void k_scanb(const int* __restrict__ T,
                                               int* __restrict__ bbase, int nbuck) {
  __shared__ int sh[256];
  __shared__ int carry;
  int t = threadIdx.x;
  if (t == 0) carry = 0;
  __syncthreads();
  for (int base = 0; base < nbuck; base += 256) {
    int v = (base + t < nbuck) ? T[base + t] : 0;
    sh[t] = v;
    __syncthreads();
    for (int off = 1; off < 256; off <<= 1) {
      int x = sh[t];
      int y = (t >= off) ? sh[t - off] : 0;
      __syncthreads();
      sh[t] = x + y;
      __syncthreads();
    }
    if (base + t < nbuck) bbase[base + t] = carry + sh[t] - v;
    __syncthreads();
    if (t == 255) carry += sh[255];
    __syncthreads();
  }
}

// ---------------- pass 3 FUSED: scatter (blocks < nbb) || GEMM1 unscaled ----------------

__global__ __launch_bounds__(256) void k_fused(const int* __restrict__ src,
                                               const int* __restrict__ dst,
                                               const int* __restrict__ C,
                                               const int* __restrict__ bbase,
                                               unsigned* __restrict__ packed,
                                               int E, int nbuck, int nbb,
                                               const float* __restrict__ X,
                                               const float* __restrict__ W1,
                                               __half* __restrict__ H16, int n) {
  extern __shared__ char smem[];
  int t = threadIdx.x;

  if (blockIdx.x < nbb) {
    int* baseL = (int*)smem;            // NBMX
    int* cnt   = baseL + NBMX;          // NBMX
    const int* Crow = C + (size_t)blockIdx.x * nbuck;
    for (int i = t; i < nbuck; i += 256) {
      baseL[i] = bbase[i] + Crow[i];
      cnt[i] = 0;
    }
    __syncthreads();

    int e0 = blockIdx.x * CHUNK;
    int e1 = e0 + CHUNK;
    if (e1 > E) e1 = E;
    for (int r0 = e0; r0 < e1; r0 += 1024) {
      int i0 = r0 + t * 4;
      int s4[4], d4[4];
      bool full = (i0 + 4 <= e1);
      if (full) {
        vi4 sv = __builtin_nontemporal_load((const vi4*)&src[i0]);
        vi4 dv = __builtin_nontemporal_load((const vi4*)&dst[i0]);
        s4[0] = sv.x; s4[1] = sv.y; s4[2] = sv.z; s4[3] = sv.w;
        d4[0] = dv.x; d4[1] = dv.y; d4[2] = dv.z; d4[3] = dv.w;
      } else {
        for (int q = 0; q < 4; ++q)
          if (i0 + q < e1) { s4[q] = src[i0 + q]; d4[q] = dst[i0 + q]; }
      }
#pragma unroll
      for (int q = 0; q < 4; ++q) {
        if (i0 + q < e1) {
          int b = d4[q] >> 6;
          int slot = atomicAdd(&cnt[b], 1);
          packed[(size_t)baseL[b] + slot] =
              ((unsigned)s4[q] << 6) | (unsigned)(d4[q] & 63);
        }
      }
    }
  } else {
    float* Wl = (float*)smem;          // 64*64
    float* Xl = Wl + 4096;             // 64 rows, stride XPAD
    const int row0 = (blockIdx.x - nbb) * 64;
    const int tc = t & 15;
    const int tr = t >> 4;
    float acc[4][4] = {};

    for (int k0 = 0; k0 < NFEAT; k0 += 64) {
      __syncthreads();
#pragma unroll
      for (int i = 0; i < 4; ++i) {
        int idx = t * 4 + i * 1024;
        int kr = idx >> 6, c = idx & 63;
        *(vf4*)&Wl[idx] = *(const vf4*)&W1[(size_t)(k0 + kr) * 64 + c];
      }
#pragma unroll
      for (int i = 0; i < 4; ++i) {
        int idx = t * 4 + i * 1024;
        int r = idx >> 6, c = idx & 63;
        int row = row0 + r;
        vf4 v = {0.f, 0.f, 0.f, 0.f};
        if (row < n) v = __builtin_nontemporal_load((const vf4*)&X[(size_t)row * NFEAT + k0 + c]);
        *(vf4*)&Xl[r * XPAD + c] = v;
      }
      __syncthreads();
#pragma unroll 4
      for (int kk = 0; kk < 64; kk += 4) {
        float4 xv[4], wv[4];
#pragma unroll
        for (int r = 0; r < 4; ++r) xv[r] = *(float4*)&Xl[(tr * 4 + r) * XPAD + kk];
#pragma unroll
        for (int q = 0; q < 4; ++q) wv[q] = *(float4*)&Wl[(kk + q) * 64 + tc * 4];
#pragma unroll
        for (int r = 0; r < 4; ++r) {
          const float xr[4] = {xv[r].x, xv[r].y, xv[r].z, xv[r].w};
#pragma unroll
          for (int q = 0; q < 4; ++q) {
            acc[r][0] += xr[q] * wv[q].x;
            acc[r][1] += xr[q] * wv[q].y;
            acc[r][2] += xr[q] * wv[q].z;
            acc[r][3] += xr[q] * wv[q].w;
          }
        }
      }
    }
#pragma unroll
    for (int r = 0; r < 4; ++r) {
      int row = row0 + tr * 4 + r;
      if (row < n) {
        __half2 h01 = __floats2half2_rn(acc[r][0], acc[r][1]);
        __half2 h23 = __floats2half2_rn(acc[r][2], acc[r][3]);
        uint2 st;
        st.x = *reinterpret_cast<unsigned*>(&h01);
        st.y = *reinterpret_cast<unsigned*>(&h23);
        ((uint2*)H16)[(size_t)row * 16 + tc] = st;
      }
    }
  }
}

// ---------------- build: in-LDS counting sort + in-place dis-scaling of this bucket's g1 rows ----------------

__global__ __launch_bounds__(256) void k_build(unsigned* __restrict__ packed,
                                               const int* __restrict__ T,
                                               const int* __restrict__ bbase,
                                               int2* __restrict__ rowrange,
                                               float* __restrict__ dis,
                                               __half* __restrict__ g1,   // scaled in place (own rows only)
                                               int n, int nbuck) {
  __shared__ unsigned buf[CAPB];
  __shared__ unsigned outb[CAPB];
  __shared__ int cnt4[4][64];
  __shared__ int cur4[4][64];
  __shared__ int offi[64];
  __shared__ int offx[64];
  __shared__ int cntl[64];
  __shared__ float disl[64];
  int b = blockIdx.x;
  int t = threadIdx.x;
  int g = t >> 6;
  int m = T[b];
  if (m > CAPB) m = CAPB;
  int bb = bbase[b];
  unsigned* pb = packed + bb;

  cnt4[g][t & 63] = 0;
  for (int k = t; k < m; k += 256) buf[k] = pb[k];
  __syncthreads();
  for (int k = t; k < m; k += 256) atomicAdd(&cnt4[g][buf[k] & 63u], 1);
  __syncthreads();
  if (t < 64) {
    int c0 = cnt4[0][t], c1 = cnt4[1][t], c2 = cnt4[2][t], c3 = cnt4[3][t];
    int tot = c0 + c1 + c2 + c3;
    cntl[t] = tot;
    offi[t] = tot;
    cur4[0][t] = 0;
    cur4[1][t] = c0;
    cur4[2][t] = c0 + c1;
    cur4[3][t] = c0 + c1 + c2;
  }
  __syncthreads();
  for (int off = 1; off < 64; off <<= 1) {
    int x = (t < 64) ? offi[t] : 0;
    int y = (t >= off && t < 64) ? offi[t - off] : 0;
    __syncthreads();
    if (t < 64) offi[t] = x + y;
    __syncthreads();
  }
  if (t < 64) {
    offx[t] = offi[t] - cntl[t];
    float dv = rsqrtf((float)cntl[t] + 1.0f);  // +1 self-loop
    disl[t] = dv;
    int v = b * 64 + t;
    if (v < n) {
      rowrange[v] = make_int2(bb + offx[t], cntl[t]);
      dis[v] = dv;
    }
#pragma unroll
    for (int gg = 0; gg < 4; ++gg) cur4[gg][t] += offx[t];
  }
  __syncthreads();
  for (int k = t; k < m; k += 256) {
    unsigned e = buf[k];
    int dl = e & 63u;
    int q = atomicAdd(&cur4[g][dl], 1);
    outb[q] = e >> 6;
  }
  __syncthreads();
  for (int k = t; k < m; k += 256) pb[k] = outb[k];  // packed becomes srcs

  // scale this bucket's 64 g1 rows by dis (race-free: block owns these rows)
  __half2* g1h = (__half2*)g1;
#pragma unroll
  for (int i = 0; i < 8; ++i) {
    int idx = t + i * 256;            // 0..2047
    int r = idx >> 5, e = idx & 31;
    int v = b * 64 + r;
    if (v < n) {
      size_t p = (size_t)v * 32 + e;
      float2 f = __half22float2(g1h[p]);
      float d = disl[r];
      g1h[p] = __floats2half2_rn(f.x * d, f.y * d);
    }
  }
}

// ---------------- FUSED layer 1: agg (pre-scaled msgs) + ReLU + @W2 (in-group shfl) -> g2 fp16 ----------------

__global__ __launch_bounds__(256) void k_agg_gemm(const int2* __restrict__ rowrange,
                                                  const int* __restrict__ srcs,
                                                  const __half* __restrict__ g16,
                                                  const float* __restrict__ dis,
                                                  const float* __restrict__ b1,
                                                  const float* __restrict__ W2,
                                                  __half* __restrict__ g2out, int n) {
  __shared__ __half2 W2h[64 * 32];  // 8KB, row k at W2h[k*32 + c/2]
  int t = threadIdx.x;
  for (int i = t; i < 2048; i += 256) {
    float2 f = *(const float2*)&W2[(size_t)i * 2];
    W2h[i] = __floats2half2_rn(f.x, f.y);
  }
  __syncthreads();  // W2h ready BEFORE gather; no sync after

  int grp = t >> 4, lane = t & 15;
  int v = blockIdx.x * 16 + grp;
  if (v >= n) return;
  const uint2* g2 = (const uint2*)g16;

  int2 rr = rowrange[v];
  int j = rr.x, end = rr.x + rr.y;
  uint2 su = g2[(size_t)v * 16 + lane];
  float2 f0 = __half22float2(*reinterpret_cast<__half2*>(&su.x));
  float2 f1 = __half22float2(*reinterpret_cast<__half2*>(&su.y));
  float ax = f0.x, ay = f0.y, az = f1.x, aw = f1.y;

  for (; j + 8 <= end; j += 8) {
    int s[8];
#pragma unroll
    for (int q = 0; q < 8; ++q) s[q] = __builtin_nontemporal_load(&srcs[j + q]);
    uint2 a[8];
#pragma unroll
    for (int q = 0; q < 8; ++q) a[q] = g2[(size_t)s[q] * 16 + lane];
#pragma unroll
    for (int q = 0; q < 8; ++q) {
      float2 p0 = __half22float2(*reinterpret_cast<__half2*>(&a[q].x));
      float2 p1 = __half22float2(*reinterpret_cast<__half2*>(&a[q].y));
      ax += p0.x; ay += p0.y; az += p1.x; aw += p1.y;
    }
  }
  for (; j < end; ++j) {
    int s0 = __builtin_nontemporal_load(&srcs[j]);
    uint2 a0 = g2[(size_t)s0 * 16 + lane];
    float2 p0 = __half22float2(*reinterpret_cast<__half2*>(&a0.x));
    float2 p1 = __half22float2(*reinterpret_cast<__half2*>(&a0.y));
    ax += p0.x; ay += p0.y; az += p1.x; aw += p1.y;
  }

  float dv = dis[v];
  float4 bb = *(const float4*)&b1[lane * 4];
  float r0 = fmaxf(fmaf(dv, ax, bb.x), 0.f);
  float r1 = fmaxf(fmaf(dv, ay, bb.y), 0.f);
  float r2 = fmaxf(fmaf(dv, az, bb.z), 0.f);
  float r3 = fmaxf(fmaf(dv, aw, bb.w), 0.f);

  float o0 = 0.f, o1 = 0.f, o2 = 0.f, o3 = 0.f;
  int gbase = (t & 63) & 48;  // group base lane within wave
  int c2 = lane * 2;
#pragma unroll
  for (int kk = 0; kk < 16; ++kk) {
    int sl = gbase + kk;
    float a0 = __shfl(r0, sl, 64);
    float a1 = __shfl(r1, sl, 64);
    float a2 = __shfl(r2, sl, 64);
    float a3 = __shfl(r3, sl, 64);
    int k = kk * 4;
    float2 w;
    w = __half22float2(W2h[(k + 0) * 32 + c2]);     o0 = fmaf(a0, w.x, o0); o1 = fmaf(a0, w.y, o1);
    w = __half22float2(W2h[(k + 0) * 32 + c2 + 1]); o2 = fmaf(a0, w.x, o2); o3 = fmaf(a0, w.y, o3);
    w = __half22float2(W2h[(k + 1) * 32 + c2]);     o0 = fmaf(a1, w.x, o0); o1 = fmaf(a1, w.y, o1);
    w = __half22float2(W2h[(k + 1) * 32 + c2 + 1]); o2 = fmaf(a1, w.x, o2); o3 = fmaf(a1, w.y, o3);
    w = __half22float2(W2h[(k + 2) * 32 + c2]);     o0 = fmaf(a2, w.x, o0); o1 = fmaf(a2, w.y, o1);
    w = __half22float2(W2h[(k + 2) * 32 + c2 + 1]); o2 = fmaf(a2, w.x, o2); o3 = fmaf(a2, w.y, o3);
    w = __half22float2(W2h[(k + 3) * 32 + c2]);     o0 = fmaf(a3, w.x, o0); o1 = fmaf(a3, w.y, o1);
    w = __half22float2(W2h[(k + 3) * 32 + c2 + 1]); o2 = fmaf(a3, w.x, o2); o3 = fmaf(a3, w.y, o3);
  }
  __half2 h01 = __floats2half2_rn(o0 * dv, o1 * dv);
  __half2 h23 = __floats2half2_rn(o2 * dv, o3 * dv);
  uint2 st;
  st.x = *reinterpret_cast<unsigned*>(&h01);
  st.y = *reinterpret_cast<unsigned*>(&h23);
  ((uint2*)g2out)[(size_t)v * 16 + lane] = st;
}

// ---------------- FUSED layer 2: agg (pre-scaled msgs) + ReLU + @Wfc + bfc -> out ----------------

__global__ __launch_bounds__(256) void k_agg_fc(const int2* __restrict__ rowrange,
                                                const int* __restrict__ srcs,
                                                const __half* __restrict__ g16,
                                                const float* __restrict__ dis,
                                                const float* __restrict__ b2,
                                                const float* __restrict__ Wfc,
                                                const float* __restrict__ bfc,
                                                float* __restrict__ outp, int n) {
  __shared__ float Wl[64 * NCLS];
  __shared__ float bl[8];
  int t = threadIdx.x;
  for (int i = t; i < 64 * NCLS; i += 256) Wl[i] = Wfc[i];
  if (t < NCLS) bl[t] = bfc[t];
  __syncthreads();

  int grp = t >> 4, lane = t & 15;
  int v = blockIdx.x * 16 + grp;
  bool active = (v < n);
  const uint2* g2 = (const uint2*)g16;

  float r0 = 0.f, r1 = 0.f, r2 = 0.f, r3 = 0.f;
  if (active) {
    int2 rr = rowrange[v];
    int j = rr.x, end = rr.x + rr.y;
    uint2 su = g2[(size_t)v * 16 + lane];
    float2 f0 = __half22float2(*reinterpret_cast<__half2*>(&su.x));
    float2 f1 = __half22float2(*reinterpret_cast<__half2*>(&su.y));
    float ax = f0.x, ay = f0.y, az = f1.x, aw = f1.y;

    for (; j + 8 <= end; j += 8) {
      int s[8];
#pragma unroll
      for (int q = 0; q < 8; ++q) s[q] = __builtin_nontemporal_load(&srcs[j + q]);
      uint2 a[8];
#pragma unroll
      for (int q = 0; q < 8; ++q) a[q] = g2[(size_t)s[q] * 16 + lane];
#pragma unroll
      for (int q = 0; q < 8; ++q) {
        float2 p0 = __half22float2(*reinterpret_cast<__half2*>(&a[q].x));
        float2 p1 = __half22float2(*reinterpret_cast<__half2*>(&a[q].y));
        ax += p0.x; ay += p0.y; az += p1.x; aw += p1.y;
      }
    }
    for (; j < end; ++j) {
      int s0 = __builtin_nontemporal_load(&srcs[j]);
      uint2 a0 = g2[(size_t)s0 * 16 + lane];
      float2 p0 = __half22float2(*reinterpret_cast<__half2*>(&a0.x));
      float2 p1 = __half22float2(*reinterpret_cast<__half2*>(&a0.y));
      ax += p0.x; ay += p0.y; az += p1.x; aw += p1.y;
    }
    float dv = dis[v];
    float4 bb = *(const float4*)&b2[lane * 4];
    r0 = fmaxf(fmaf(dv, ax, bb.x), 0.f);
    r1 = fmaxf(fmaf(dv, ay, bb.y), 0.f);
    r2 = fmaxf(fmaf(dv, az, bb.z), 0.f);
    r3 = fmaxf(fmaf(dv, aw, bb.w), 0.f);
  }

  float p[NCLS];
#pragma unroll
  for (int jj = 0; jj < NCLS; ++jj) p[jj] = 0.f;
  int k0 = lane * 4;
#pragma unroll
  for (int q = 0; q < 4; ++q) {
    float a = (q == 0) ? r0 : (q == 1) ? r1 : (q == 2) ? r2 : r3;
#pragma unroll
    for (int jj = 0; jj < NCLS; ++jj)
      p[jj] = fmaf(a, Wl[(k0 + q) * NCLS + jj], p[jj]);
  }
#pragma unroll
  for (int m = 1; m < 16; m <<= 1) {
#pragma unroll
    for (int jj = 0; jj < NCLS; ++jj)
      p[jj] += __shfl_xor(p[jj], m, 64);
  }
  if (active && lane < NCLS)
    outp[(size_t)v * NCLS + lane] = p[lane] + bl[lane];
}

// ---------------- launch ----------------

extern "C" void kernel_launch(void* const* d_in, const int* in_sizes, int n_in,
                              void* d_out, int out_size, void* d_ws, size_t ws_size,
                              hipStream_t stream) {
  const float* x   = (const float*)d_in[0];
  const int*   ei  = (const int*)d_in[1];
  const float* W1  = (const float*)d_in[2];
  const float* b1  = (const float*)d_in[3];
  const float* W2  = (const float*)d_in[4];
  const float* b2  = (const float*)d_in[5];
  const float* Wfc = (const float*)d_in[6];
  const float* bfc = (const float*)d_in[7];
  float* out = (float*)d_out;

  const int n = in_sizes[0] / NFEAT;   // 100000
  const int E = in_sizes[1] / 2;       // 3200000
  const int* src = ei;
  const int* dst = ei + E;
  const int nbuck = (n + 63) >> 6;     // 1563 (<= NBMX)
  const int nbb = (E + CHUNK - 1) / CHUNK;  // 196 count/scatter blocks
  const int ntile = (n + 63) / 64;     // 1563 gemm tiles

  char* ws = (char*)d_ws;
  size_t off = 0;
  auto alloc = [&](size_t bytes) -> void* {
    void* p = (void*)(ws + off);
    off += (bytes + 255) & ~(size_t)255;
    return p;
  };
  float* dis      = (float*)alloc((size_t)n * 4);
  int2*  rowrange = (int2*)alloc((size_t)n * 8);
  int*   C        = (int*)alloc((size_t)nbb * nbuck * 4);   // 1.2MB count matrix
  int*   T        = (int*)alloc((size_t)nbuck * 4);
  int*   bbase    = (int*)alloc((size_t)nbuck * 4);
  unsigned* packed = (unsigned*)alloc((size_t)E * 4);       // 12.8MB dense; becomes srcs
  __half* bufA16  = (__half*)alloc((size_t)n * HID * 2);    // g1 (12.8MB), dis-scaled by k_build
  __half* bufC16  = (__half*)alloc((size_t)n * HID * 2);    // g2 (12.8MB)

  // ---- deterministic 3-pass CSR build; pass 3 runs || gemm1 ----
  k_count<<<nbb, 256, 0, stream>>>(dst, C, E, nbuck);
  k_scan_cols<<<(nbuck + 255) / 256, 256, 0, stream>>>(C, T, nbb, nbuck);
  k_scanb<<<1, 256, 0, stream>>>(T, bbase, nbuck);
  k_fused<<<nbb + ntile, 256, FUSED_LDS, stream>>>(src, dst, C, bbase, packed,
                                                   E, nbuck, nbb, x, W1, bufA16, n);
  k_build<<<nbuck, 256, 0, stream>>>(packed, T, bbase, rowrange, dis, bufA16, n, nbuck);

  // ---- layer 1 agg + gemm2 fused -> g2 ----
  k_agg_gemm<<<(n + 15) / 16, 256, 0, stream>>>(rowrange, (const int*)packed, bufA16,
                                                dis, b1, W2, bufC16, n);

  // ---- layer 2 agg + FC fused -> out ----
  k_agg_fc<<<(n + 15) / 16, 256, 0, stream>>>(rowrange, (const int*)packed, bufC16,
                                              dis, b2, Wfc, bfc, out, n);
}